// Round 8
// baseline (266.855 us; speedup 1.0000x reference)
//
#include <hip/hip_runtime.h>
#include <hip/hip_bf16.h>
#include <math.h>

#define D 128
#define NGRAPH 16

typedef __attribute__((ext_vector_type(8))) short bf16x8;   // 8 bf16 (4 VGPRs)
typedef __attribute__((ext_vector_type(4))) float f32x4;    // MFMA C/D

// Column permutation: original col c = half*64 + nf*16 + fr  (fr=0..15, nf=0..3)
// stored at permuted col c' = half*64 + fr*4 + nf.
// -> register-direct stores from the MFMA C/D layout are fully coalesced.
// Dot products / weighted sums are invariant; final_kernel unpermutes.

__device__ __forceinline__ float bflo(unsigned u) {
    union { unsigned i; float f; } v; v.i = u << 16; return v.f;
}
__device__ __forceinline__ float bfhi(unsigned u) {
    union { unsigned i; float f; } v; v.i = u & 0xffff0000u; return v.f;
}
__device__ __forceinline__ unsigned pack_bf16(float x, float y) {
    __hip_bfloat16 hx = __float2bfloat16(x);
    __hip_bfloat16 hy = __float2bfloat16(y);
    unsigned ux = *(const unsigned short*)&hx;
    unsigned uy = *(const unsigned short*)&hy;
    return ux | (uy << 16);
}

// ---------------------------------------------------------------------------
// Stage A: edge count by dst + W1..4 -> bf16 [m][col][k] + permuted W5/b5 f32
// ---------------------------------------------------------------------------
__global__ void count_wconv_kernel(const int* __restrict__ dstIdx,
                                   int* __restrict__ cnt, int E,
                                   const float* __restrict__ W1, const float* __restrict__ W2,
                                   const float* __restrict__ W3, const float* __restrict__ W4,
                                   const float* __restrict__ W5, const float* __restrict__ b5,
                                   __hip_bfloat16* __restrict__ Wbt,
                                   float* __restrict__ w5p, float* __restrict__ b5p)
{
    int id = blockIdx.x * 256 + threadIdx.x;
    if (id < E) atomicAdd(&cnt[dstIdx[id]], 1);
    if (id < 4 * D * D) {
        int mm  = id >> 14;
        int rem = id & 16383;
        int c   = rem >> 7;
        int k   = rem & 127;
        const float* Wm = (mm == 0) ? W1 : (mm == 1) ? W2 : (mm == 2) ? W3 : W4;
        Wbt[id] = __float2bfloat16(Wm[k * D + c]);
    }
    if (id < D) {   // permuted W5 row / b5:  c' = half*64 + fr*4 + nf
        int half = id >> 6;
        int rem  = id & 63;
        int fr   = rem >> 2;
        int nf   = rem & 3;
        int c = half * 64 + nf * 16 + fr;
        w5p[id] = W5[c];
        b5p[id] = b5[c];
    }
}

// ---------------------------------------------------------------------------
// Stage B: all four projections, bf16 MFMA, permuted coalesced direct stores.
// 512 threads = 8 waves; wave wv owns rows (wv>>1)*32..+31, cols (wv&1)*64..+63.
// Per wave: a-frags 4kk x 2mf (32 VGPRs), acc 2x4 (32 VGPRs) -> low pressure,
// __launch_bounds__(512,4) pins VGPR <= 128 for >=2 blocks/CU.
// Outputs (bf16, permuted): x1b,x3b,x4b,x2b each [N][64] uints; uint2 stores
// are 128B contiguous per 16-lane fq-group.
// ---------------------------------------------------------------------------
__global__ __launch_bounds__(512, 4) void proj8_kernel(
    const float* __restrict__ X,
    const __hip_bfloat16* __restrict__ Wbt,  // [4][col][k]
    const float* __restrict__ b1, const float* __restrict__ b2,
    const float* __restrict__ b3, const float* __restrict__ b4,
    unsigned* __restrict__ x1b, unsigned* __restrict__ x2b,
    unsigned* __restrict__ x3b, unsigned* __restrict__ x4b,
    int N)
{
    __shared__ __hip_bfloat16 Xs[128][136];

    const int nodeBase = blockIdx.x * 128;
    const int tid      = threadIdx.x;

    // ---- stage X (fp32 -> bf16), 512 threads: 32 cols per thread ----
    {
        int r  = tid >> 2;            // 0..127
        int k0 = (tid & 3) * 32;
        int row = nodeBase + r;
        if (row >= N) row = N - 1;
        const float* src = X + (size_t)row * D + k0;
        #pragma unroll
        for (int i = 0; i < 4; ++i) {
            float4 u = *(const float4*)(src + i * 8);
            float4 v = *(const float4*)(src + i * 8 + 4);
            __hip_bfloat16 h[8];
            h[0] = __float2bfloat16(u.x); h[1] = __float2bfloat16(u.y);
            h[2] = __float2bfloat16(u.z); h[3] = __float2bfloat16(u.w);
            h[4] = __float2bfloat16(v.x); h[5] = __float2bfloat16(v.y);
            h[6] = __float2bfloat16(v.z); h[7] = __float2bfloat16(v.w);
            *(uint4*)&Xs[r][k0 + i * 8] = *(const uint4*)h;
        }
    }
    __syncthreads();

    const int wv   = tid >> 6;        // 0..7
    const int lane = tid & 63;
    const int wr   = (wv >> 1) * 32;  // row base (32 rows/wave)
    const int half = wv & 1;
    const int wc   = half * 64;
    const int fr   = lane & 15;
    const int fq   = lane >> 4;

    bf16x8 a[4][2];                   // [kk][mf]
    #pragma unroll
    for (int kk = 0; kk < 4; ++kk)
        #pragma unroll
        for (int mf = 0; mf < 2; ++mf)
            a[kk][mf] = *(const bf16x8*)&Xs[wr + mf * 16 + fr][kk * 32 + fq * 8];
    // Xs not reused; no further barriers.

    #pragma unroll
    for (int m = 0; m < 4; ++m) {
        const __hip_bfloat16* Wm = Wbt + (size_t)m * D * D;
        f32x4 acc[2][4] = {};

        #pragma unroll
        for (int kk = 0; kk < 4; ++kk) {
            bf16x8 b[4];
            #pragma unroll
            for (int nf = 0; nf < 4; ++nf)
                b[nf] = *(const bf16x8*)(Wm + (size_t)(wc + nf * 16 + fr) * D
                                            + kk * 32 + fq * 8);
            #pragma unroll
            for (int mf = 0; mf < 2; ++mf)
                #pragma unroll
                for (int nf = 0; nf < 4; ++nf)
                    acc[mf][nf] = __builtin_amdgcn_mfma_f32_16x16x32_bf16(
                        a[kk][mf], b[nf], acc[mf][nf], 0, 0, 0);
        }

        const float* bias = (m == 0) ? b1 : (m == 1) ? b2 : (m == 2) ? b3 : b4;
        unsigned* Out = (m == 0) ? x1b : (m == 1) ? x2b : (m == 2) ? x3b : x4b;
        float bv[4];
        #pragma unroll
        for (int nf = 0; nf < 4; ++nf) bv[nf] = bias[wc + nf * 16 + fr];

        #pragma unroll
        for (int mf = 0; mf < 2; ++mf) {
            #pragma unroll
            for (int j = 0; j < 4; ++j) {
                int row = nodeBase + wr + mf * 16 + fq * 4 + j;
                if (row < N) {
                    uint2 v;
                    v.x = pack_bf16(acc[mf][0][j] + bv[0], acc[mf][1][j] + bv[1]);
                    v.y = pack_bf16(acc[mf][2][j] + bv[2], acc[mf][3][j] + bv[3]);
                    *(uint2*)(Out + (size_t)row * 64 + half * 32 + fr * 2) = v;
                }
            }
        }
    }
}

// ---------------------------------------------------------------------------
// Stage C: scans
// ---------------------------------------------------------------------------
__global__ __launch_bounds__(256) void scan1(const int* __restrict__ cnt,
                                             int* __restrict__ row_off,
                                             int* __restrict__ bsum, int N)
{
    __shared__ int s[256];
    int tid = threadIdx.x;
    int i0  = blockIdx.x * 1024 + tid * 4;
    int v[4];
    #pragma unroll
    for (int j = 0; j < 4; ++j) v[j] = (i0 + j < N) ? cnt[i0 + j] : 0;
    int t = v[0] + v[1] + v[2] + v[3];
    s[tid] = t;
    __syncthreads();
    for (int off = 1; off < 256; off <<= 1) {
        int y = 0;
        if (tid >= off) y = s[tid - off];
        __syncthreads();
        s[tid] += y;
        __syncthreads();
    }
    int run = s[tid] - t;
    #pragma unroll
    for (int j = 0; j < 4; ++j) {
        if (i0 + j < N) row_off[i0 + j] = run;
        run += v[j];
    }
    if (tid == 255) bsum[blockIdx.x] = s[255];
}

__global__ void scan2(int* __restrict__ bsum, int nb)
{
    int lane = threadIdx.x;  // blockDim = 64
    int a = (lane < nb) ? bsum[lane] : 0;
    int b = (64 + lane < nb) ? bsum[64 + lane] : 0;
    int xa = a;
    #pragma unroll
    for (int off = 1; off < 64; off <<= 1) {
        int y = __shfl_up(xa, off);
        if (lane >= off) xa += y;
    }
    int totA = __shfl(xa, 63);
    int xb = b;
    #pragma unroll
    for (int off = 1; off < 64; off <<= 1) {
        int y = __shfl_up(xb, off);
        if (lane >= off) xb += y;
    }
    if (lane < nb) bsum[lane] = xa - a;
    if (64 + lane < nb) bsum[64 + lane] = totA + xb - b;
}

// ---------------------------------------------------------------------------
// Stage D: fill (row_off doubles as cursor; node recovers start later)
// ---------------------------------------------------------------------------
__global__ void fill_kernel(const int* __restrict__ srcIdx,
                            const int* __restrict__ dstIdx,
                            const float* __restrict__ eattr,
                            int* __restrict__ row_off,
                            const int* __restrict__ bsum,
                            int2* __restrict__ src_attr, int E)
{
    int e = blockIdx.x * 256 + threadIdx.x;
    if (e < E) {
        int d = dstIdx[e];
        int p = atomicAdd(&row_off[d], 1);
        int2 rec;
        rec.x = srcIdx[e];
        rec.y = __float_as_int(eattr[e]);
        src_attr[p + bsum[d >> 10]] = rec;
    }
}

// ---------------------------------------------------------------------------
// Stage E0: per-node p,q = x3 . W5row, x3 . b5 (permuted space, consistent).
// ---------------------------------------------------------------------------
__global__ __launch_bounds__(256) void pq_kernel(
    const unsigned* __restrict__ x3b,
    const float* __restrict__ w5p, const float* __restrict__ b5p,
    float2* __restrict__ pq, int N)
{
    int n = blockIdx.x * 8 + (threadIdx.x >> 5);
    if (n >= N) return;
    int l5 = threadIdx.x & 31;
    uint2 u  = *(const uint2*)(x3b + (size_t)n * 64 + l5 * 2);
    float4 w = *(const float4*)(w5p + l5 * 4);
    float4 b = *(const float4*)(b5p + l5 * 4);
    float x0 = bflo(u.x), x1 = bfhi(u.x), x2 = bflo(u.y), x3 = bfhi(u.y);
    float p = x0 * w.x + x1 * w.y + x2 * w.z + x3 * w.w;
    float q = x0 * b.x + x1 * b.y + x2 * b.z + x3 * b.w;
    #pragma unroll
    for (int off = 16; off; off >>= 1) {
        p += __shfl_xor(p, off);
        q += __shfl_xor(q, off);
    }
    if (l5 == 0) pq[n] = make_float2(p, q);
}

// ---------------------------------------------------------------------------
// Stage E: per-dst-node attention + aggregation. One wave per node, two
// 32-lane halves x 2 edges each per iteration. Per edge per lane: two uint2
// gathers (x4b for the dot, x2b for the accumulate) at the same index.
// Rescale only when the running max actually increases.
// ---------------------------------------------------------------------------
__global__ __launch_bounds__(256) void node_kernel(
    unsigned* __restrict__ x1b,                // [N][64] uints; in/out
    const unsigned* __restrict__ x4b,          // [N][64]
    const unsigned* __restrict__ x2b,          // [N][64]
    const unsigned* __restrict__ x3b,          // [N][64]
    const float2* __restrict__ pq,
    const int* __restrict__ row_off,
    const int* __restrict__ cnt,
    const int* __restrict__ bsum,
    const int2* __restrict__ src_attr,
    int N)
{
    int n    = blockIdx.x * 4 + (threadIdx.x >> 6);
    int lane = threadIdx.x & 63;
    if (n >= N) return;
    int h  = lane >> 5;
    int l5 = lane & 31;

    uint2 a3u = *(const uint2*)(x3b + (size_t)n * 64 + l5 * 2);
    float a0 = bflo(a3u.x), a1 = bfhi(a3u.x), a2 = bflo(a3u.y), a3v = bfhi(a3u.y);
    float2 pqv = pq[n];

    const int deg   = cnt[n];
    const int start = row_off[n] + bsum[n >> 10] - deg;
    const int2* sa  = src_attr + start;
    const float inv_sqrt_d = 0.08838834764831845f;  // 1/sqrt(128)

    float mrun = -INFINITY, z = 0.f;
    float acc0 = 0.f, acc1 = 0.f, acc2 = 0.f, acc3 = 0.f;

    for (int i = 0; i < deg; i += 4) {
        int e0 = i + h;
        int e1 = i + 2 + h;
        int c0 = min(e0, deg - 1);
        int c1 = min(e1, deg - 1);
        int2 r0 = sa[c0];
        int2 r1 = sa[c1];
        uint2 f40 = *(const uint2*)(x4b + (size_t)r0.x * 64 + l5 * 2);
        uint2 f41 = *(const uint2*)(x4b + (size_t)r1.x * 64 + l5 * 2);
        uint2 f20 = *(const uint2*)(x2b + (size_t)r0.x * 64 + l5 * 2);
        uint2 f21 = *(const uint2*)(x2b + (size_t)r1.x * 64 + l5 * 2);

        float d0 = a0 * bflo(f40.x) + a1 * bfhi(f40.x) + a2 * bflo(f40.y) + a3v * bfhi(f40.y);
        float d1 = a0 * bflo(f41.x) + a1 * bfhi(f41.x) + a2 * bflo(f41.y) + a3v * bfhi(f41.y);
        #pragma unroll
        for (int off = 16; off; off >>= 1) {
            d0 += __shfl_xor(d0, off);
            d1 += __shfl_xor(d1, off);
        }
        float s0 = (d0 + __int_as_float(r0.y) * pqv.x + pqv.y) * inv_sqrt_d;
        float s1 = (d1 + __int_as_float(r1.y) * pqv.x + pqv.y) * inv_sqrt_d;
        if (e0 >= deg) s0 = -INFINITY;
        if (e1 >= deg) s1 = -INFINITY;

        float tm = fmaxf(s0, s1);
        tm = fmaxf(tm, __shfl_xor(tm, 32));
        if (tm > mrun) {                       // wave-uniform rescale branch
            float sc = __expf(mrun - tm);      // 0 on first iteration
            z *= sc; acc0 *= sc; acc1 *= sc; acc2 *= sc; acc3 *= sc;
            mrun = tm;
        }
        float w0 = __expf(s0 - mrun);          // 0 for masked edges
        float w1 = __expf(s1 - mrun);
        z += w0 + w1;
        acc0 += w0 * bflo(f20.x) + w1 * bflo(f21.x);
        acc1 += w0 * bfhi(f20.x) + w1 * bfhi(f21.x);
        acc2 += w0 * bflo(f20.y) + w1 * bflo(f21.y);
        acc3 += w0 * bfhi(f20.y) + w1 * bfhi(f21.y);
    }

    z    += __shfl_xor(z, 32);
    acc0 += __shfl_xor(acc0, 32);
    acc1 += __shfl_xor(acc1, 32);
    acc2 += __shfl_xor(acc2, 32);
    acc3 += __shfl_xor(acc3, 32);

    if (h == 0) {
        uint2 u1 = *(const uint2*)(x1b + (size_t)n * 64 + l5 * 2);
        float o0 = bflo(u1.x), o1 = bfhi(u1.x), o2 = bflo(u1.y), o3 = bfhi(u1.y);
        if (deg > 0) {
            float inv = 1.f / z;
            o0 += acc0 * inv; o1 += acc1 * inv; o2 += acc2 * inv; o3 += acc3 * inv;
        }
        uint2 o; o.x = pack_bf16(o0, o1); o.y = pack_bf16(o2, o3);
        *(uint2*)(x1b + (size_t)n * 64 + l5 * 2) = o;
    }
}

// ---------------------------------------------------------------------------
// Stage F: global mean pool (permuted space)
// ---------------------------------------------------------------------------
__global__ __launch_bounds__(256) void pool_kernel(
    const unsigned* __restrict__ node_out,     // [N][64] uints
    const int* __restrict__ batch,
    float* __restrict__ pooled,
    float* __restrict__ cntf,
    int N)
{
    int c   = threadIdx.x & 63;
    int sub = threadIdx.x >> 6;
    int nodesPerBlock = (N + gridDim.x - 1) / gridDim.x;
    int startN = blockIdx.x * nodesPerBlock;
    int endN   = min(startN + nodesPerBlock, N);

    float ax = 0.f, ay = 0.f, cct = 0.f;
    int gcur = -1;
    for (int n = startN + sub; n < endN; n += 4) {
        int gg = batch[n];
        unsigned u = node_out[(size_t)n * 64 + c];
        if (gg != gcur) {
            if (gcur >= 0) {
                atomicAdd(&pooled[gcur * D + c * 2], ax);
                atomicAdd(&pooled[gcur * D + c * 2 + 1], ay);
                if (c == 0) atomicAdd(&cntf[gcur], cct);
            }
            gcur = gg; ax = 0.f; ay = 0.f; cct = 0.f;
        }
        ax += bflo(u); ay += bfhi(u); cct += 1.f;
    }
    if (gcur >= 0) {
        atomicAdd(&pooled[gcur * D + c * 2], ax);
        atomicAdd(&pooled[gcur * D + c * 2 + 1], ay);
        if (c == 0) atomicAdd(&cntf[gcur], cct);
    }
}

// final: divide by counts and UNPERMUTE columns (c' = half*64 + fr*4 + nf)
__global__ void final_kernel(const float* __restrict__ pooled,
                             const float* __restrict__ cntf,
                             float* __restrict__ out)
{
    int i = blockIdx.x * 256 + threadIdx.x;
    if (i < NGRAPH * D) {
        int c    = i & 127;                    // original column
        int fr   = c & 15;
        int nf   = (c >> 4) & 3;
        int half = c >> 6;
        int cp   = half * 64 + fr * 4 + nf;    // permuted column
        float cval = cntf[i >> 7];
        out[i] = pooled[(i & ~127) + cp] / fmaxf(cval, 1.f);
    }
}

// ---------------------------------------------------------------------------
extern "C" void kernel_launch(void* const* d_in, const int* in_sizes, int n_in,
                              void* d_out, int out_size, void* d_ws, size_t ws_size,
                              hipStream_t stream)
{
    const float* x     = (const float*)d_in[0];
    const int*   eidx  = (const int*)d_in[1];   // [2,E]: src = eidx[e], dst = eidx[E+e]
    const float* eattr = (const float*)d_in[2];
    const int*   batch = (const int*)d_in[3];
    const float* W1 = (const float*)d_in[4];  const float* b1 = (const float*)d_in[5];
    const float* W2 = (const float*)d_in[6];  const float* b2 = (const float*)d_in[7];
    const float* W3 = (const float*)d_in[8];  const float* b3 = (const float*)d_in[9];
    const float* W4 = (const float*)d_in[10]; const float* b4 = (const float*)d_in[11];
    const float* W5 = (const float*)d_in[12]; const float* b5 = (const float*)d_in[13];
    float* out = (float*)d_out;

    const int N = in_sizes[0] / D;
    const int E = in_sizes[1] / 2;

    // workspace layout
    char* ws = (char*)d_ws;
    unsigned* x1b = (unsigned*)ws;                          // [N][64] uints
    unsigned* x2b = x1b + (size_t)N * 64;
    unsigned* x3b = x2b + (size_t)N * 64;
    unsigned* x4b = x3b + (size_t)N * 64;
    int* cnt      = (int*)(x4b + (size_t)N * 64);
    int* row_off  = cnt + N;
    int2* src_attr = (int2*)(row_off + N);
    int* bsum     = (int*)(src_attr + E);
    float* pooled = (float*)(bsum + 256);
    float* cntf   = pooled + NGRAPH * D;
    float2* pq    = (float2*)(cntf + NGRAPH);
    __hip_bfloat16* Wbt = (__hip_bfloat16*)(pq + N);
    float* w5p = (float*)(Wbt + 4 * D * D);
    float* b5p = w5p + D;

    hipMemsetAsync(cnt, 0, (size_t)N * sizeof(int), stream);
    hipMemsetAsync(pooled, 0, (size_t)(NGRAPH * D + NGRAPH) * sizeof(float), stream);

    int cblocks = (E + 255) / 256;
    int wblocks = (4 * D * D + 255) / 256;
    count_wconv_kernel<<<(cblocks > wblocks ? cblocks : wblocks), 256, 0, stream>>>(
        eidx + E, cnt, E, W1, W2, W3, W4, W5, b5, Wbt, w5p, b5p);

    int nb = (N + 1023) / 1024;
    scan1<<<nb, 256, 0, stream>>>(cnt, row_off, bsum, N);
    scan2<<<1, 64, 0, stream>>>(bsum, nb);
    fill_kernel<<<(E + 255) / 256, 256, 0, stream>>>(eidx, eidx + E, eattr,
                                                     row_off, bsum, src_attr, E);

    proj8_kernel<<<(N + 127) / 128, 512, 0, stream>>>(x, Wbt, b1, b2, b3, b4,
                                                      x1b, x2b, x3b, x4b, N);

    pq_kernel<<<(N + 7) / 8, 256, 0, stream>>>(x3b, w5p, b5p, pq, N);

    node_kernel<<<(N + 3) / 4, 256, 0, stream>>>(x1b, x4b, x2b, x3b, pq,
                                                 row_off, cnt, bsum, src_attr, N);

    pool_kernel<<<256, 256, 0, stream>>>(x1b, batch, pooled, cntf, N);
    final_kernel<<<(NGRAPH * D + 255) / 256, 256, 0, stream>>>(pooled, cntf, out);
}

// Round 9
// 258.275 us; speedup vs baseline: 1.0332x; 1.0332x over previous
//
#include <hip/hip_runtime.h>
#include <hip/hip_bf16.h>
#include <math.h>

#define D 128
#define NGRAPH 16

typedef __attribute__((ext_vector_type(8))) short bf16x8;   // 8 bf16 (4 VGPRs)
typedef __attribute__((ext_vector_type(4))) float f32x4;    // MFMA C/D

// Column permutation: original col c = half*64 + nf*16 + fr  (fr=0..15, nf=0..3)
// stored at permuted col c' = half*64 + fr*4 + nf.
// Dot products / weighted sums are invariant; final_kernel unpermutes.
// x1 is NEVER materialized: pooled x1 = mean_g(x) @ W1 + b1 (computed in final
// from xsum accumulated in proj9). node writes pure aggr.

__device__ __forceinline__ float bflo(unsigned u) {
    union { unsigned i; float f; } v; v.i = u << 16; return v.f;
}
__device__ __forceinline__ float bfhi(unsigned u) {
    union { unsigned i; float f; } v; v.i = u & 0xffff0000u; return v.f;
}
__device__ __forceinline__ float bfbits(unsigned short us) {
    union { unsigned i; float f; } v; v.i = ((unsigned)us) << 16; return v.f;
}
__device__ __forceinline__ unsigned pack_bf16(float x, float y) {
    __hip_bfloat16 hx = __float2bfloat16(x);
    __hip_bfloat16 hy = __float2bfloat16(y);
    unsigned ux = *(const unsigned short*)&hx;
    unsigned uy = *(const unsigned short*)&hy;
    return ux | (uy << 16);
}

// ---------------------------------------------------------------------------
// Stage A: edge count by dst + W2..4 -> bf16 [m][col][k] + permuted W5/b5 f32
// ---------------------------------------------------------------------------
__global__ void count_wconv_kernel(const int* __restrict__ dstIdx,
                                   int* __restrict__ cnt, int E,
                                   const float* __restrict__ W1, const float* __restrict__ W2,
                                   const float* __restrict__ W3, const float* __restrict__ W4,
                                   const float* __restrict__ W5, const float* __restrict__ b5,
                                   __hip_bfloat16* __restrict__ Wbt,
                                   float* __restrict__ w5p, float* __restrict__ b5p)
{
    int id = blockIdx.x * 256 + threadIdx.x;
    if (id < E) atomicAdd(&cnt[dstIdx[id]], 1);
    if (id < 4 * D * D) {
        int mm  = id >> 14;
        int rem = id & 16383;
        int c   = rem >> 7;
        int k   = rem & 127;
        const float* Wm = (mm == 0) ? W1 : (mm == 1) ? W2 : (mm == 2) ? W3 : W4;
        Wbt[id] = __float2bfloat16(Wm[k * D + c]);
    }
    if (id < D) {   // permuted W5 row / b5:  c' = half*64 + fr*4 + nf
        int half = id >> 6;
        int rem  = id & 63;
        int fr   = rem >> 2;
        int nf   = rem & 3;
        int c = half * 64 + nf * 16 + fr;
        w5p[id] = W5[c];
        b5p[id] = b5[c];
    }
}

// ---------------------------------------------------------------------------
// Stage B: projections W2,W3,W4 via bf16 MFMA, permuted coalesced stores.
// 512 threads = 8 waves; wave wv owns rows (wv>>1)*32..+31, cols (wv&1)*64..+63.
// During the W3 (x3) pass, per-row p=x3.W5 and q=x3.b5 partials are reduced
// over the 16-lane fr group and atomicAdd'ed into pq[n] (both halves add).
// After the m-loop, threads tid<128 accumulate per-graph column sums of X
// (xsum, original columns) from the LDS tile using the sorted-batch run trick.
// ---------------------------------------------------------------------------
__global__ __launch_bounds__(512, 4) void proj9_kernel(
    const float* __restrict__ X,
    const __hip_bfloat16* __restrict__ Wbt,  // [4][col][k]
    const float* __restrict__ b2, const float* __restrict__ b3,
    const float* __restrict__ b4,
    const float* __restrict__ w5p, const float* __restrict__ b5p,
    const int* __restrict__ batch,
    unsigned* __restrict__ x2b, unsigned* __restrict__ x3b,
    unsigned* __restrict__ x4b,
    float* __restrict__ pq,                  // [N][2] (p,q), pre-zeroed
    float* __restrict__ xsum,                // [16][128] fp32, pre-zeroed
    int N)
{
    __shared__ __hip_bfloat16 Xs[128][136];
    __shared__ int batch_s[128];

    const int nodeBase = blockIdx.x * 128;
    const int tid      = threadIdx.x;

    // ---- stage X (fp32 -> bf16), 512 threads: 32 cols per thread ----
    {
        int r  = tid >> 2;            // 0..127
        int k0 = (tid & 3) * 32;
        int row = nodeBase + r;
        if (row >= N) row = N - 1;
        const float* src = X + (size_t)row * D + k0;
        #pragma unroll
        for (int i = 0; i < 4; ++i) {
            float4 u = *(const float4*)(src + i * 8);
            float4 v = *(const float4*)(src + i * 8 + 4);
            __hip_bfloat16 h[8];
            h[0] = __float2bfloat16(u.x); h[1] = __float2bfloat16(u.y);
            h[2] = __float2bfloat16(u.z); h[3] = __float2bfloat16(u.w);
            h[4] = __float2bfloat16(v.x); h[5] = __float2bfloat16(v.y);
            h[6] = __float2bfloat16(v.z); h[7] = __float2bfloat16(v.w);
            *(uint4*)&Xs[r][k0 + i * 8] = *(const uint4*)h;
        }
        if (tid < 128) {
            int rr = nodeBase + tid;
            batch_s[tid] = (rr < N) ? batch[rr] : 0;
        }
    }
    __syncthreads();

    const int wv   = tid >> 6;        // 0..7
    const int lane = tid & 63;
    const int wr   = (wv >> 1) * 32;  // row base (32 rows/wave)
    const int half = wv & 1;
    const int wc   = half * 64;
    const int fr   = lane & 15;
    const int fq   = lane >> 4;

    bf16x8 a[4][2];                   // [kk][mf]
    #pragma unroll
    for (int kk = 0; kk < 4; ++kk)
        #pragma unroll
        for (int mf = 0; mf < 2; ++mf)
            a[kk][mf] = *(const bf16x8*)&Xs[wr + mf * 16 + fr][kk * 32 + fq * 8];

    float4 w5v = *(const float4*)(w5p + half * 64 + fr * 4);
    float4 b5v = *(const float4*)(b5p + half * 64 + fr * 4);

    #pragma unroll
    for (int mi = 0; mi < 3; ++mi) {
        const int m = mi + 1;                       // 1:x2, 2:x3, 3:x4
        const __hip_bfloat16* Wm = Wbt + (size_t)m * D * D;
        f32x4 acc[2][4] = {};

        #pragma unroll
        for (int kk = 0; kk < 4; ++kk) {
            bf16x8 b[4];
            #pragma unroll
            for (int nf = 0; nf < 4; ++nf)
                b[nf] = *(const bf16x8*)(Wm + (size_t)(wc + nf * 16 + fr) * D
                                            + kk * 32 + fq * 8);
            #pragma unroll
            for (int mf = 0; mf < 2; ++mf)
                #pragma unroll
                for (int nf = 0; nf < 4; ++nf)
                    acc[mf][nf] = __builtin_amdgcn_mfma_f32_16x16x32_bf16(
                        a[kk][mf], b[nf], acc[mf][nf], 0, 0, 0);
        }

        const float* bias = (m == 1) ? b2 : (m == 2) ? b3 : b4;
        unsigned* Out = (m == 1) ? x2b : (m == 2) ? x3b : x4b;
        float bv[4];
        #pragma unroll
        for (int nf = 0; nf < 4; ++nf) bv[nf] = bias[wc + nf * 16 + fr];

        #pragma unroll
        for (int mf = 0; mf < 2; ++mf) {
            #pragma unroll
            for (int j = 0; j < 4; ++j) {
                int row = nodeBase + wr + mf * 16 + fq * 4 + j;
                float c0v = acc[mf][0][j] + bv[0];
                float c1v = acc[mf][1][j] + bv[1];
                float c2v = acc[mf][2][j] + bv[2];
                float c3v = acc[mf][3][j] + bv[3];
                if (row < N) {
                    uint2 v;
                    v.x = pack_bf16(c0v, c1v);
                    v.y = pack_bf16(c2v, c3v);
                    *(uint2*)(Out + (size_t)row * 64 + half * 32 + fr * 2) = v;
                }
                if (m == 2) {   // p,q partials for this row (this half's 64 cols)
                    float vp = c0v * w5v.x + c1v * w5v.y + c2v * w5v.z + c3v * w5v.w;
                    float vq = c0v * b5v.x + c1v * b5v.y + c2v * b5v.z + c3v * b5v.w;
                    #pragma unroll
                    for (int off = 1; off < 16; off <<= 1) {
                        vp += __shfl_xor(vp, off);
                        vq += __shfl_xor(vq, off);
                    }
                    if (fr == 0 && row < N) {
                        atomicAdd(&pq[2 * row],     vp);
                        atomicAdd(&pq[2 * row + 1], vq);
                    }
                }
            }
        }
    }

    // ---- per-graph column sums of X (original columns) ----
    if (tid < 128) {
        int nv = N - nodeBase; if (nv > 128) nv = 128;
        float s = 0.f; int gcur = -1;
        for (int r = 0; r < nv; ++r) {
            int gg = batch_s[r];
            float v = bfbits(*(const unsigned short*)&Xs[r][tid]);
            if (gg != gcur) {
                if (gcur >= 0) atomicAdd(&xsum[gcur * D + tid], s);
                gcur = gg; s = 0.f;
            }
            s += v;
        }
        if (gcur >= 0) atomicAdd(&xsum[gcur * D + tid], s);
    }
}

// ---------------------------------------------------------------------------
// Stage C: scans
// ---------------------------------------------------------------------------
__global__ __launch_bounds__(256) void scan1(const int* __restrict__ cnt,
                                             int* __restrict__ row_off,
                                             int* __restrict__ bsum, int N)
{
    __shared__ int s[256];
    int tid = threadIdx.x;
    int i0  = blockIdx.x * 1024 + tid * 4;
    int v[4];
    #pragma unroll
    for (int j = 0; j < 4; ++j) v[j] = (i0 + j < N) ? cnt[i0 + j] : 0;
    int t = v[0] + v[1] + v[2] + v[3];
    s[tid] = t;
    __syncthreads();
    for (int off = 1; off < 256; off <<= 1) {
        int y = 0;
        if (tid >= off) y = s[tid - off];
        __syncthreads();
        s[tid] += y;
        __syncthreads();
    }
    int run = s[tid] - t;
    #pragma unroll
    for (int j = 0; j < 4; ++j) {
        if (i0 + j < N) row_off[i0 + j] = run;
        run += v[j];
    }
    if (tid == 255) bsum[blockIdx.x] = s[255];
}

__global__ void scan2(int* __restrict__ bsum, int nb)
{
    int lane = threadIdx.x;  // blockDim = 64
    int a = (lane < nb) ? bsum[lane] : 0;
    int b = (64 + lane < nb) ? bsum[64 + lane] : 0;
    int xa = a;
    #pragma unroll
    for (int off = 1; off < 64; off <<= 1) {
        int y = __shfl_up(xa, off);
        if (lane >= off) xa += y;
    }
    int totA = __shfl(xa, 63);
    int xb = b;
    #pragma unroll
    for (int off = 1; off < 64; off <<= 1) {
        int y = __shfl_up(xb, off);
        if (lane >= off) xb += y;
    }
    if (lane < nb) bsum[lane] = xa - a;
    if (64 + lane < nb) bsum[64 + lane] = totA + xb - b;
}

// ---------------------------------------------------------------------------
// Stage D: fill (row_off doubles as cursor; node recovers start later)
// ---------------------------------------------------------------------------
__global__ void fill_kernel(const int* __restrict__ srcIdx,
                            const int* __restrict__ dstIdx,
                            const float* __restrict__ eattr,
                            int* __restrict__ row_off,
                            const int* __restrict__ bsum,
                            int2* __restrict__ src_attr, int E)
{
    int e = blockIdx.x * 256 + threadIdx.x;
    if (e < E) {
        int d = dstIdx[e];
        int p = atomicAdd(&row_off[d], 1);
        int2 rec;
        rec.x = srcIdx[e];
        rec.y = __float_as_int(eattr[e]);
        src_attr[p + bsum[d >> 10]] = rec;
    }
}

// ---------------------------------------------------------------------------
// Stage E: per-dst-node attention + aggregation. One wave per node, two
// 32-lane halves x 2 edges each per iteration. Writes pure aggr (bf16).
// ---------------------------------------------------------------------------
__global__ __launch_bounds__(256) void node_kernel(
    unsigned* __restrict__ aggrb,              // [N][64] uints; write-only
    const unsigned* __restrict__ x4b,          // [N][64]
    const unsigned* __restrict__ x2b,          // [N][64]
    const unsigned* __restrict__ x3b,          // [N][64]
    const float* __restrict__ pq,              // [N][2]
    const int* __restrict__ row_off,
    const int* __restrict__ cnt,
    const int* __restrict__ bsum,
    const int2* __restrict__ src_attr,
    int N)
{
    int n    = blockIdx.x * 4 + (threadIdx.x >> 6);
    int lane = threadIdx.x & 63;
    if (n >= N) return;
    int h  = lane >> 5;
    int l5 = lane & 31;

    uint2 a3u = *(const uint2*)(x3b + (size_t)n * 64 + l5 * 2);
    float a0 = bflo(a3u.x), a1 = bfhi(a3u.x), a2 = bflo(a3u.y), a3v = bfhi(a3u.y);
    float pv = pq[2 * n], qv = pq[2 * n + 1];

    const int deg   = cnt[n];
    const int start = row_off[n] + bsum[n >> 10] - deg;
    const int2* sa  = src_attr + start;
    const float inv_sqrt_d = 0.08838834764831845f;  // 1/sqrt(128)

    float mrun = -INFINITY, z = 0.f;
    float acc0 = 0.f, acc1 = 0.f, acc2 = 0.f, acc3 = 0.f;

    for (int i = 0; i < deg; i += 4) {
        int e0 = i + h;
        int e1 = i + 2 + h;
        int c0 = min(e0, deg - 1);
        int c1 = min(e1, deg - 1);
        int2 r0 = sa[c0];
        int2 r1 = sa[c1];
        uint2 f40 = *(const uint2*)(x4b + (size_t)r0.x * 64 + l5 * 2);
        uint2 f41 = *(const uint2*)(x4b + (size_t)r1.x * 64 + l5 * 2);
        uint2 f20 = *(const uint2*)(x2b + (size_t)r0.x * 64 + l5 * 2);
        uint2 f21 = *(const uint2*)(x2b + (size_t)r1.x * 64 + l5 * 2);

        float d0 = a0 * bflo(f40.x) + a1 * bfhi(f40.x) + a2 * bflo(f40.y) + a3v * bfhi(f40.y);
        float d1 = a0 * bflo(f41.x) + a1 * bfhi(f41.x) + a2 * bflo(f41.y) + a3v * bfhi(f41.y);
        #pragma unroll
        for (int off = 16; off; off >>= 1) {
            d0 += __shfl_xor(d0, off);
            d1 += __shfl_xor(d1, off);
        }
        float s0 = (d0 + __int_as_float(r0.y) * pv + qv) * inv_sqrt_d;
        float s1 = (d1 + __int_as_float(r1.y) * pv + qv) * inv_sqrt_d;
        if (e0 >= deg) s0 = -INFINITY;
        if (e1 >= deg) s1 = -INFINITY;

        float tm = fmaxf(s0, s1);
        tm = fmaxf(tm, __shfl_xor(tm, 32));
        if (tm > mrun) {                       // wave-uniform rescale branch
            float sc = __expf(mrun - tm);      // 0 on first iteration
            z *= sc; acc0 *= sc; acc1 *= sc; acc2 *= sc; acc3 *= sc;
            mrun = tm;
        }
        float w0 = __expf(s0 - mrun);          // 0 for masked edges
        float w1 = __expf(s1 - mrun);
        z += w0 + w1;
        acc0 += w0 * bflo(f20.x) + w1 * bflo(f21.x);
        acc1 += w0 * bfhi(f20.x) + w1 * bfhi(f21.x);
        acc2 += w0 * bflo(f20.y) + w1 * bflo(f21.y);
        acc3 += w0 * bfhi(f20.y) + w1 * bfhi(f21.y);
    }

    z    += __shfl_xor(z, 32);
    acc0 += __shfl_xor(acc0, 32);
    acc1 += __shfl_xor(acc1, 32);
    acc2 += __shfl_xor(acc2, 32);
    acc3 += __shfl_xor(acc3, 32);

    if (h == 0) {
        float o0 = 0.f, o1 = 0.f, o2 = 0.f, o3 = 0.f;
        if (deg > 0) {
            float inv = 1.f / z;
            o0 = acc0 * inv; o1 = acc1 * inv; o2 = acc2 * inv; o3 = acc3 * inv;
        }
        uint2 o; o.x = pack_bf16(o0, o1); o.y = pack_bf16(o2, o3);
        *(uint2*)(aggrb + (size_t)n * 64 + l5 * 2) = o;
    }
}

// ---------------------------------------------------------------------------
// Stage F: global mean pool of aggr (permuted space) + node counts
// ---------------------------------------------------------------------------
__global__ __launch_bounds__(256) void pool_kernel(
    const unsigned* __restrict__ aggrb,        // [N][64] uints
    const int* __restrict__ batch,
    float* __restrict__ pooled,
    float* __restrict__ cntf,
    int N)
{
    int c   = threadIdx.x & 63;
    int sub = threadIdx.x >> 6;
    int nodesPerBlock = (N + gridDim.x - 1) / gridDim.x;
    int startN = blockIdx.x * nodesPerBlock;
    int endN   = min(startN + nodesPerBlock, N);

    float ax = 0.f, ay = 0.f, cct = 0.f;
    int gcur = -1;
    for (int n = startN + sub; n < endN; n += 4) {
        int gg = batch[n];
        unsigned u = aggrb[(size_t)n * 64 + c];
        if (gg != gcur) {
            if (gcur >= 0) {
                atomicAdd(&pooled[gcur * D + c * 2], ax);
                atomicAdd(&pooled[gcur * D + c * 2 + 1], ay);
                if (c == 0) atomicAdd(&cntf[gcur], cct);
            }
            gcur = gg; ax = 0.f; ay = 0.f; cct = 0.f;
        }
        ax += bflo(u); ay += bfhi(u); cct += 1.f;
    }
    if (gcur >= 0) {
        atomicAdd(&pooled[gcur * D + c * 2], ax);
        atomicAdd(&pooled[gcur * D + c * 2 + 1], ay);
        if (c == 0) atomicAdd(&cntf[gcur], cct);
    }
}

// final: out[g][c] = (pooled_aggr[g][perm(c)] + xsum[g].W1[:,c] + cnt*b1[c])/cnt
__global__ void final_kernel(const float* __restrict__ pooled,
                             const float* __restrict__ cntf,
                             const float* __restrict__ xsum,
                             const float* __restrict__ W1,
                             const float* __restrict__ b1,
                             float* __restrict__ out)
{
    int i = blockIdx.x * 256 + threadIdx.x;
    if (i < NGRAPH * D) {
        int g    = i >> 7;
        int c    = i & 127;                    // original column
        int fr   = c & 15;
        int nf   = (c >> 4) & 3;
        int half = c >> 6;
        int cp   = half * 64 + fr * 4 + nf;    // permuted column
        float cval = cntf[g];
        float acc = pooled[g * D + cp];
        float w1dot = 0.f;
        for (int k = 0; k < D; ++k)
            w1dot += xsum[g * D + k] * W1[k * D + c];
        out[i] = (acc + w1dot + cval * b1[c]) / fmaxf(cval, 1.f);
    }
}

// ---------------------------------------------------------------------------
extern "C" void kernel_launch(void* const* d_in, const int* in_sizes, int n_in,
                              void* d_out, int out_size, void* d_ws, size_t ws_size,
                              hipStream_t stream)
{
    const float* x     = (const float*)d_in[0];
    const int*   eidx  = (const int*)d_in[1];   // [2,E]: src = eidx[e], dst = eidx[E+e]
    const float* eattr = (const float*)d_in[2];
    const int*   batch = (const int*)d_in[3];
    const float* W1 = (const float*)d_in[4];  const float* b1 = (const float*)d_in[5];
    const float* W2 = (const float*)d_in[6];  const float* b2 = (const float*)d_in[7];
    const float* W3 = (const float*)d_in[8];  const float* b3 = (const float*)d_in[9];
    const float* W4 = (const float*)d_in[10]; const float* b4 = (const float*)d_in[11];
    const float* W5 = (const float*)d_in[12]; const float* b5 = (const float*)d_in[13];
    float* out = (float*)d_out;

    const int N = in_sizes[0] / D;
    const int E = in_sizes[1] / 2;

    // workspace layout
    char* ws = (char*)d_ws;
    unsigned* aggrb = (unsigned*)ws;                        // [N][64] uints
    unsigned* x2b = aggrb + (size_t)N * 64;
    unsigned* x3b = x2b + (size_t)N * 64;
    unsigned* x4b = x3b + (size_t)N * 64;
    int* cnt      = (int*)(x4b + (size_t)N * 64);
    int* row_off  = cnt + N;
    int2* src_attr = (int2*)(row_off + N);
    int* bsum     = (int*)(src_attr + E);
    // zero-region: pooled | cntf | xsum | pq  (one memset)
    float* pooled = (float*)(bsum + 256);
    float* cntf   = pooled + NGRAPH * D;
    float* xsum   = cntf + NGRAPH;
    float* pq     = xsum + NGRAPH * D;                      // [N][2]
    __hip_bfloat16* Wbt = (__hip_bfloat16*)(pq + 2 * (size_t)N);
    float* w5p = (float*)(Wbt + 4 * D * D);
    float* b5p = w5p + D;

    size_t zero_bytes = (size_t)(NGRAPH * D + NGRAPH + NGRAPH * D) * sizeof(float)
                      + 2 * (size_t)N * sizeof(float);
    hipMemsetAsync(cnt, 0, (size_t)N * sizeof(int), stream);
    hipMemsetAsync(pooled, 0, zero_bytes, stream);

    int cblocks = (E + 255) / 256;
    int wblocks = (4 * D * D + 255) / 256;
    count_wconv_kernel<<<(cblocks > wblocks ? cblocks : wblocks), 256, 0, stream>>>(
        eidx + E, cnt, E, W1, W2, W3, W4, W5, b5, Wbt, w5p, b5p);

    int nb = (N + 1023) / 1024;
    scan1<<<nb, 256, 0, stream>>>(cnt, row_off, bsum, N);
    scan2<<<1, 64, 0, stream>>>(bsum, nb);
    fill_kernel<<<(E + 255) / 256, 256, 0, stream>>>(eidx, eidx + E, eattr,
                                                     row_off, bsum, src_attr, E);

    proj9_kernel<<<(N + 127) / 128, 512, 0, stream>>>(x, Wbt, b2, b3, b4,
                                                      w5p, b5p, batch,
                                                      x2b, x3b, x4b, pq, xsum, N);

    node_kernel<<<(N + 3) / 4, 256, 0, stream>>>(aggrb, x4b, x2b, x3b, pq,
                                                 row_off, cnt, bsum, src_attr, N);

    pool_kernel<<<256, 256, 0, stream>>>(aggrb, batch, pooled, cntf, N);
    final_kernel<<<(NGRAPH * D + 255) / 256, 256, 0, stream>>>(pooled, cntf, xsum,
                                                               W1, b1, out);
}